// Round 7
// baseline (638.817 us; speedup 1.0000x reference)
//
#include <hip/hip_runtime.h>

#define DEV __device__ __forceinline__

// ---------- vector types ----------
typedef float          f32x4  __attribute__((ext_vector_type(4)));
typedef unsigned int   u32x4  __attribute__((ext_vector_type(4)));
typedef unsigned short u16x4  __attribute__((ext_vector_type(4)));
typedef __bf16         vbf8   __attribute__((ext_vector_type(8)));
typedef short          vs8    __attribute__((ext_vector_type(8)));

typedef f32x4 f32x4_a __attribute__((may_alias));
typedef u32x4 u32x4_a __attribute__((may_alias));
typedef u16x4 u16x4_a __attribute__((may_alias));

// ---------- bf16 helpers (RNE) ----------
DEV unsigned short f2bf(float f) {
  unsigned int u = __float_as_uint(f);
  u += 0x7fffu + ((u >> 16) & 1u);
  return (unsigned short)(u >> 16);
}

// ---------- MFMA shim (v8 bf16 vs v8 i16 builtin prototypes) ----------
struct MfmaNope {};
template <class T, class U> struct SameT { static constexpr bool value = false; };
template <class T> struct SameT<T, T> { static constexpr bool value = true; };

template <typename A>
DEV auto mfma_try(A a, A b, f32x4 c, int)
    -> decltype(__builtin_amdgcn_mfma_f32_16x16x32_bf16(a, b, c, 0, 0, 0)) {
  return __builtin_amdgcn_mfma_f32_16x16x32_bf16(a, b, c, 0, 0, 0);
}
template <typename A>
DEV MfmaNope mfma_try(A, A, f32x4, long) { return MfmaNope{}; }

template <typename I4 = u32x4>
DEV f32x4 mfma_bf16(I4 a, I4 b, f32x4 c) {
  auto r = mfma_try(__builtin_bit_cast(vbf8, a), __builtin_bit_cast(vbf8, b), c, 0);
  if constexpr (SameT<decltype(r), MfmaNope>::value) {
    return mfma_try(__builtin_bit_cast(vs8, a), __builtin_bit_cast(vs8, b), c, 0);
  } else {
    return r;
  }
}

// Fragment layout (16x16x32 bf16):
//   A[m][k]: m=lane&15, k=(lane>>4)*8+j ; B[k][n]: n=lane&15, k=(lane>>4)*8+j
//   C[m][n]: n=lane&15, m=(lane>>4)*4+reg
// Softmax in exp2-domain: Q pre-scaled by 0.125*log2(e) in k_qkv,
// k_stats emits c[s] = max_q(S') + log2(sum_q 2^(S'-max)), k_attn: P=2^(S'-c).
// LDS pads: row stride 72 u16 (= 36 dw == 4 mod 32) -> b128 frag reads free.
// r6 post-mortem: k_attn was latency-bound at 2 blocks/CU; V/Q fragments are
// now gathered directly from L2-resident global (16x64B lines per wave),
// LDS cut to Ks+Ps (36.9KB) -> 4 blocks/CU.
#define QSCL 0.18033688011112042f  // 0.125 * log2(e)

// =====================================================================
// Kernel 1: LayerNorm fp32 -> bf16   (8192 rows of 1024)
// =====================================================================
__global__ __launch_bounds__(256) void k_ln(const float* __restrict__ x,
                                            unsigned short* __restrict__ xn) {
  const int row = blockIdx.x;
  const int t = threadIdx.x;
  f32x4 v = *reinterpret_cast<const f32x4_a*>(x + (size_t)row * 1024 + t * 4);
  float s = v[0] + v[1] + v[2] + v[3];
  float q = v[0]*v[0] + v[1]*v[1] + v[2]*v[2] + v[3]*v[3];
#pragma unroll
  for (int o = 32; o > 0; o >>= 1) { s += __shfl_xor(s, o); q += __shfl_xor(q, o); }
  __shared__ float rs_[4], rq_[4];
  const int w = t >> 6;
  if ((t & 63) == 0) { rs_[w] = s; rq_[w] = q; }
  __syncthreads();
  s = rs_[0] + rs_[1] + rs_[2] + rs_[3];
  q = rq_[0] + rq_[1] + rq_[2] + rq_[3];
  const float mu = s * (1.0f / 1024.0f);
  const float rstd = rsqrtf(q * (1.0f / 1024.0f) - mu * mu + 1e-5f);
  u16x4 o;
#pragma unroll
  for (int i = 0; i < 4; ++i) o[i] = f2bf((v[i] - mu) * rstd);
  *reinterpret_cast<u16x4_a*>(xn + (size_t)row * 1024 + t * 4) = o;
}

// =====================================================================
// Kernel 2a: repack Wq/Wk/Wv [16][1024][64] fp32 -> Wt rows [3072][1024] bf16
// =====================================================================
__global__ __launch_bounds__(256) void k_repw(const float* __restrict__ Wq,
                                              const float* __restrict__ Wk,
                                              const float* __restrict__ Wv,
                                              unsigned short* __restrict__ Wt) {
  __shared__ float ld[64][65];
  const int d0 = blockIdx.x * 64;
  const int sh = blockIdx.y;
  const int sel = sh >> 4, h = sh & 15;
  const float* W = (sel == 0) ? Wq : (sel == 1) ? Wk : Wv;
  const float* src = W + (size_t)h * 1024 * 64;
  const int t = threadIdx.x;
#pragma unroll
  for (int r = 0; r < 16; ++r) {
    const int e = t + 256 * r;
    const int dl = e >> 6, k = e & 63;
    ld[dl][k] = src[(size_t)(d0 + dl) * 64 + k];
  }
  __syncthreads();
#pragma unroll
  for (int r = 0; r < 16; ++r) {
    const int e = t + 256 * r;
    const int k = e >> 6, dl = e & 63;
    Wt[(size_t)(sel * 1024 + h * 64 + k) * 1024 + d0 + dl] = f2bf(ld[dl][k]);
  }
}

// Kernel 2b: cast Wo fp32 -> bf16
__global__ __launch_bounds__(256) void k_repo(const float* __restrict__ Wo,
                                              unsigned short* __restrict__ WoT) {
  const int j = blockIdx.x, t = threadIdx.x;
  f32x4 v = *reinterpret_cast<const f32x4_a*>(Wo + (size_t)j * 1024 + t * 4);
  u16x4 o;
#pragma unroll
  for (int i = 0; i < 4; ++i) o[i] = f2bf(v[i]);
  *reinterpret_cast<u16x4_a*>(WoT + (size_t)j * 1024 + t * 4) = o;
}

// =====================================================================
// Kernel 3: QKV GEMM. Q pre-scaled by QSCL; V written TRANSPOSED
// Vt[bh][64][2048] via u16x4 stores (r-quad = 4 consecutive s). grid (24,64).
// =====================================================================
__global__ __launch_bounds__(256) void k_qkv(const unsigned short* __restrict__ A,
                                             const unsigned short* __restrict__ Bt,
                                             const float* __restrict__ bq,
                                             const float* __restrict__ bk,
                                             const float* __restrict__ bv,
                                             unsigned short* __restrict__ Qo,
                                             unsigned short* __restrict__ Ko,
                                             unsigned short* __restrict__ Vt) {
  __shared__ __align__(16) unsigned short As[128][72];
  __shared__ __align__(16) unsigned short Bs[128][72];
  const int bn = blockIdx.x, bm = blockIdx.y;
  const int t = threadIdx.x;
  const int w = t >> 6, lane = t & 63, l15 = lane & 15, g = lane >> 4;
  const int wm = w & 1, wn = w >> 1;
  f32x4 acc[4][4] = {};
  const int am0 = bm * 128, bn0 = bn * 128;
  for (int kt = 0; kt < 16; ++kt) {
    const int k0 = kt * 64;
    __syncthreads();
#pragma unroll
    for (int r = 0; r < 4; ++r) {
      const int ci = t + 256 * r;
      const int row = ci >> 3, c8 = (ci & 7) * 8;
      *reinterpret_cast<u32x4_a*>(&As[row][c8]) =
          *reinterpret_cast<const u32x4_a*>(A + (size_t)(am0 + row) * 1024 + k0 + c8);
      *reinterpret_cast<u32x4_a*>(&Bs[row][c8]) =
          *reinterpret_cast<const u32x4_a*>(Bt + (size_t)(bn0 + row) * 1024 + k0 + c8);
    }
    __syncthreads();
#pragma unroll
    for (int kf = 0; kf < 2; ++kf) {
      u32x4 af[4], bf[4];
#pragma unroll
      for (int i = 0; i < 4; ++i)
        af[i] = *reinterpret_cast<const u32x4_a*>(&As[wm * 64 + i * 16 + l15][kf * 32 + g * 8]);
#pragma unroll
      for (int j = 0; j < 4; ++j)
        bf[j] = *reinterpret_cast<const u32x4_a*>(&Bs[wn * 64 + j * 16 + l15][kf * 32 + g * 8]);
#pragma unroll
      for (int i = 0; i < 4; ++i)
#pragma unroll
        for (int j = 0; j < 4; ++j)
          acc[i][j] = mfma_bf16(af[i], bf[j], acc[i][j]);
    }
  }
  const int sel = bn0 >> 10;
  if (sel == 2) {
    // V^T epilogue: Vt[(b*16+h)*64 + v][s], r-quad = 4 consecutive s
#pragma unroll
    for (int j = 0; j < 4; ++j) {
      const int n10 = (bn0 + wn * 64 + j * 16 + l15) & 1023;
      const float bval = bv[n10];
      const int h = n10 >> 6, vv = n10 & 63;
#pragma unroll
      for (int i = 0; i < 4; ++i) {
        const int m0 = am0 + wm * 64 + i * 16 + g * 4;
        const int bidx = m0 >> 11, s = m0 & 2047;
        u16x4 ov;
#pragma unroll
        for (int r = 0; r < 4; ++r) ov[r] = f2bf(acc[i][j][r] + bval);
        *reinterpret_cast<u16x4_a*>(
            &Vt[((size_t)(bidx * 16 + h) * 64 + vv) * 2048 + s]) = ov;
      }
    }
  } else {
    const float* bias = (sel == 0) ? bq : bk;
    unsigned short* Out = (sel == 0) ? Qo : Ko;
    const float oscl = (sel == 0) ? QSCL : 1.0f;  // fold 1/8*log2e into Q
#pragma unroll
    for (int j = 0; j < 4; ++j) {
      const int n10 = (bn0 + wn * 64 + j * 16 + l15) & 1023;
      const float bval = bias[n10];
      const int h = n10 >> 6, kk = n10 & 63;
#pragma unroll
      for (int i = 0; i < 4; ++i) {
#pragma unroll
        for (int r = 0; r < 4; ++r) {
          const int m = am0 + wm * 64 + i * 16 + g * 4 + r;
          const int bidx = m >> 11, s = m & 2047;
          Out[((size_t)(bidx * 16 + h) * 2048 + s) * 64 + kk] =
              f2bf((acc[i][j][r] + bval) * oscl);
        }
      }
    }
  }
}

// =====================================================================
// Kernel 4: column softmax stats (exp2 domain).  grid (16, 64).
//   c[s] = max_q(S') + log2(sum_q 2^(S'-max)).
// K staged once in LDS (padded 72); Q A-frags gathered DIRECTLY from
// global per qt (16x64B lines per wave, L2-hot) -> no barriers in loop,
// LDS 22.4KB.
// =====================================================================
__global__ __launch_bounds__(256, 4) void k_stats(const unsigned short* __restrict__ Q,
                                                  const unsigned short* __restrict__ K,
                                                  float* __restrict__ cG) {
  __shared__ __align__(16) unsigned short Ks[128][72];
  __shared__ float redM[4][128], redL[4][128];
  const int sblk = blockIdx.x, bh = blockIdx.y;
  const unsigned short* Qh = Q + (size_t)bh * 2048 * 64;
  const unsigned short* Kh = K + (size_t)bh * 2048 * 64;
  const int t = threadIdx.x;
  const int w = t >> 6, lane = t & 63, l15 = lane & 15, g = lane >> 4;

#pragma unroll
  for (int r = 0; r < 4; ++r) {
    const int ci = t + 256 * r;
    const int row = ci >> 3, c8 = (ci & 7) * 8;
    *reinterpret_cast<u32x4_a*>(&Ks[row][c8]) =
        *reinterpret_cast<const u32x4_a*>(Kh + ((size_t)sblk * 128 + row) * 64 + c8);
  }
  __syncthreads();

  // hoist K B-frags once (read-only for whole kernel)
  u32x4 bf[2][8];
#pragma unroll
  for (int kf = 0; kf < 2; ++kf)
#pragma unroll
    for (int n = 0; n < 8; ++n)
      bf[kf][n] = *reinterpret_cast<const u32x4_a*>(&Ks[n * 16 + l15][kf * 32 + g * 8]);

  float m_run[8], l_run[8];
#pragma unroll
  for (int n = 0; n < 8; ++n) { m_run[n] = -1e30f; l_run[n] = 0.0f; }

  for (int qt = 0; qt < 16; ++qt) {
    f32x4 acc[2][8] = {};
#pragma unroll
    for (int kf = 0; kf < 2; ++kf) {
      u32x4 af[2];
#pragma unroll
      for (int i = 0; i < 2; ++i)
        af[i] = *reinterpret_cast<const u32x4_a*>(
            Qh + ((size_t)qt * 128 + w * 32 + i * 16 + l15) * 64 + kf * 32 + g * 8);
#pragma unroll
      for (int i = 0; i < 2; ++i)
#pragma unroll
        for (int n = 0; n < 8; ++n)
          acc[i][n] = mfma_bf16(af[i], bf[kf][n], acc[i][n]);
    }
#pragma unroll
    for (int n = 0; n < 8; ++n) {
      float mt = -1e30f;
#pragma unroll
      for (int i = 0; i < 2; ++i)
#pragma unroll
        for (int r = 0; r < 4; ++r) mt = fmaxf(mt, acc[i][n][r]);
      mt = fmaxf(mt, __shfl_xor(mt, 16));
      mt = fmaxf(mt, __shfl_xor(mt, 32));
      const float mn = fmaxf(m_run[n], mt);
      float st = 0.0f;
#pragma unroll
      for (int i = 0; i < 2; ++i)
#pragma unroll
        for (int r = 0; r < 4; ++r) st += exp2f(acc[i][n][r] - mn);
      st += __shfl_xor(st, 16);
      st += __shfl_xor(st, 32);
      l_run[n] = l_run[n] * exp2f(m_run[n] - mn) + st;
      m_run[n] = mn;
    }
  }
  if (lane < 16) {
#pragma unroll
    for (int n = 0; n < 8; ++n) {
      redM[w][n * 16 + l15] = m_run[n];
      redL[w][n * 16 + l15] = l_run[n];
    }
  }
  __syncthreads();
  if (t < 128) {
    float m = fmaxf(fmaxf(redM[0][t], redM[1][t]), fmaxf(redM[2][t], redM[3][t]));
    float l = 0.0f;
#pragma unroll
    for (int ww = 0; ww < 4; ++ww) l += redL[ww][t] * exp2f(redM[ww][t] - m);
    cG[(size_t)bh * 2048 + sblk * 128 + t] = m + log2f(l);
  }
}

// =====================================================================
// Kernel 5: PV pass.  O[q,v] = sum_s 2^(S'[q,s]-c[s]) * V[s,v].
// LDS = Ks[128][72] + Ps[128][72] = 36.9KB -> 4 blocks/CU.
// V B-frags gathered directly from global V^T (16x64B lines/wave, L2-hot).
// grid (16,64).
// =====================================================================
__global__ __launch_bounds__(256, 4) void k_attn(const unsigned short* __restrict__ Q,
                                                 const unsigned short* __restrict__ K,
                                                 const unsigned short* __restrict__ Vt,
                                                 const float* __restrict__ cG,
                                                 unsigned short* __restrict__ Xh) {
  __shared__ __align__(16) unsigned short Ks[128][72];
  __shared__ __align__(16) unsigned short Ps[128][72];
  const int qb = blockIdx.x, bh = blockIdx.y;
  const int b = bh >> 4, h = bh & 15;
  const unsigned short* Qh  = Q  + (size_t)bh * 2048 * 64;
  const unsigned short* Kh  = K  + (size_t)bh * 2048 * 64;
  const unsigned short* Vth = Vt + (size_t)bh * 64 * 2048;
  const float* cH = cG + (size_t)bh * 2048;
  const int t = threadIdx.x;
  const int w = t >> 6, lane = t & 63, l15 = lane & 15, g = lane >> 4;

  // hoist Q fragments (wave-private rows)
  u32x4 aq[2][2];
#pragma unroll
  for (int i = 0; i < 2; ++i)
#pragma unroll
    for (int kf = 0; kf < 2; ++kf)
      aq[i][kf] = *reinterpret_cast<const u32x4_a*>(
          Qh + ((size_t)qb * 128 + w * 32 + i * 16 + l15) * 64 + kf * 32 + g * 8);

  f32x4 oacc[2][4] = {};

  for (int st = 0; st < 16; ++st) {
    const int s0 = st * 128;
    __syncthreads();
#pragma unroll
    for (int r = 0; r < 4; ++r) {
      const int ci = t + 256 * r;
      const int row = ci >> 3, c8 = (ci & 7) * 8;
      *reinterpret_cast<u32x4_a*>(&Ks[row][c8]) =
          *reinterpret_cast<const u32x4_a*>(Kh + ((size_t)s0 + row) * 64 + c8);
    }
    __syncthreads();

    // S' = Q'K^T  (rows: this wave's 32 q; cols: 128 s), exp2 domain
    f32x4 sacc[2][8] = {};
#pragma unroll
    for (int kf = 0; kf < 2; ++kf) {
      u32x4 bfr[8];
#pragma unroll
      for (int n = 0; n < 8; ++n)
        bfr[n] = *reinterpret_cast<const u32x4_a*>(&Ks[n * 16 + l15][kf * 32 + g * 8]);
#pragma unroll
      for (int i = 0; i < 2; ++i)
#pragma unroll
        for (int n = 0; n < 8; ++n)
          sacc[i][n] = mfma_bf16(aq[i][kf], bfr[n], sacc[i][n]);
    }

    // two halves of 64 s-columns: P -> LDS (wave-private rows) -> PV MFMA
    // with V B-frags gathered straight from global V^T.
#pragma unroll
    for (int half = 0; half < 2; ++half) {
#pragma unroll
      for (int n = 0; n < 4; ++n) {
        const int gn = half * 4 + n;
        const float cv = cH[s0 + gn * 16 + l15];
#pragma unroll
        for (int i = 0; i < 2; ++i)
#pragma unroll
          for (int r = 0; r < 4; ++r)
            Ps[w * 32 + i * 16 + g * 4 + r][n * 16 + l15] =
                f2bf(exp2f(sacc[i][gn][r] - cv));
      }
#pragma unroll
      for (int kf = 0; kf < 2; ++kf) {
        u32x4 pa[2], bvv[4];
#pragma unroll
        for (int i = 0; i < 2; ++i)
          pa[i] = *reinterpret_cast<const u32x4_a*>(&Ps[w * 32 + i * 16 + l15][kf * 32 + g * 8]);
#pragma unroll
        for (int n = 0; n < 4; ++n)
          bvv[n] = *reinterpret_cast<const u32x4_a*>(
              Vth + (size_t)(n * 16 + l15) * 2048 + s0 + half * 64 + kf * 32 + g * 8);
#pragma unroll
        for (int i = 0; i < 2; ++i)
#pragma unroll
          for (int n = 0; n < 4; ++n)
            oacc[i][n] = mfma_bf16(pa[i], bvv[n], oacc[i][n]);
      }
    }
  }

  // write O to Xh[b*2048+q][h*64+v]
#pragma unroll
  for (int i = 0; i < 2; ++i)
#pragma unroll
    for (int n = 0; n < 4; ++n)
#pragma unroll
      for (int r = 0; r < 4; ++r) {
        const int qrow = qb * 128 + w * 32 + i * 16 + g * 4 + r;
        const int vcol = n * 16 + l15;
        Xh[((size_t)b * 2048 + qrow) * 1024 + h * 64 + vcol] = f2bf(oacc[i][n][r]);
      }
}

// =====================================================================
// Kernel 6: output projection + bias + residual -> d_out fp32. grid (8,64).
// =====================================================================
__global__ __launch_bounds__(256) void k_out(const unsigned short* __restrict__ A,
                                             const unsigned short* __restrict__ Bt,
                                             const float* __restrict__ bo,
                                             const float* __restrict__ xres,
                                             float* __restrict__ out) {
  __shared__ __align__(16) unsigned short As[128][72];
  __shared__ __align__(16) unsigned short Bs[128][72];
  const int bn = blockIdx.x, bm = blockIdx.y;
  const int t = threadIdx.x;
  const int w = t >> 6, lane = t & 63, l15 = lane & 15, g = lane >> 4;
  const int wm = w & 1, wn = w >> 1;
  f32x4 acc[4][4] = {};
  const int am0 = bm * 128, bn0 = bn * 128;
  for (int kt = 0; kt < 16; ++kt) {
    const int k0 = kt * 64;
    __syncthreads();
#pragma unroll
    for (int r = 0; r < 4; ++r) {
      const int ci = t + 256 * r;
      const int row = ci >> 3, c8 = (ci & 7) * 8;
      *reinterpret_cast<u32x4_a*>(&As[row][c8]) =
          *reinterpret_cast<const u32x4_a*>(A + (size_t)(am0 + row) * 1024 + k0 + c8);
      *reinterpret_cast<u32x4_a*>(&Bs[row][c8]) =
          *reinterpret_cast<const u32x4_a*>(Bt + (size_t)(bn0 + row) * 1024 + k0 + c8);
    }
    __syncthreads();
#pragma unroll
    for (int kf = 0; kf < 2; ++kf) {
      u32x4 af[4], bf[4];
#pragma unroll
      for (int i = 0; i < 4; ++i)
        af[i] = *reinterpret_cast<const u32x4_a*>(&As[wm * 64 + i * 16 + l15][kf * 32 + g * 8]);
#pragma unroll
      for (int j = 0; j < 4; ++j)
        bf[j] = *reinterpret_cast<const u32x4_a*>(&Bs[wn * 64 + j * 16 + l15][kf * 32 + g * 8]);
#pragma unroll
      for (int i = 0; i < 4; ++i)
#pragma unroll
        for (int j = 0; j < 4; ++j)
          acc[i][j] = mfma_bf16(af[i], bf[j], acc[i][j]);
    }
  }
#pragma unroll
  for (int j = 0; j < 4; ++j) {
    const int col = bn0 + wn * 64 + j * 16 + l15;
    const float bov = bo[col];
#pragma unroll
    for (int i = 0; i < 4; ++i) {
#pragma unroll
      for (int r = 0; r < 4; ++r) {
        const int row = am0 + wm * 64 + i * 16 + g * 4 + r;
        out[(size_t)row * 1024 + col] =
            acc[i][j][r] + bov + xres[(size_t)row * 1024 + col];
      }
    }
  }
}

// =====================================================================
// Launch
// =====================================================================
extern "C" void kernel_launch(void* const* d_in, const int* in_sizes, int n_in,
                              void* d_out, int out_size, void* d_ws, size_t ws_size,
                              hipStream_t stream) {
  const float* x  = (const float*)d_in[0];
  const float* Wq = (const float*)d_in[1];
  const float* bq = (const float*)d_in[2];
  const float* Wk = (const float*)d_in[3];
  const float* bk = (const float*)d_in[4];
  const float* Wv = (const float*)d_in[5];
  const float* bv = (const float*)d_in[6];
  const float* Wo = (const float*)d_in[7];
  const float* bo = (const float*)d_in[8];
  float* out = (float*)d_out;

  unsigned short* xn  = (unsigned short*)d_ws;          // 8192*1024 bf16
  unsigned short* Wt  = xn + (size_t)8192 * 1024;       // 4096*1024 bf16
  unsigned short* Qb  = Wt + (size_t)4096 * 1024;       // [bh][2048][64] (pre-scaled)
  unsigned short* Kb  = Qb + (size_t)8192 * 1024;       // [bh][2048][64]
  unsigned short* Vtb = Kb + (size_t)8192 * 1024;       // [bh][64][2048]  (V^T)
  float* cGp  = (float*)(Vtb + (size_t)8192 * 1024);    // [bh][2048] fused stats
  unsigned short* XhB = (unsigned short*)(cGp + 2 * 131072);

  k_ln<<<8192, 256, 0, stream>>>(x, xn);
  k_repw<<<dim3(16, 48), 256, 0, stream>>>(Wq, Wk, Wv, Wt);
  k_repo<<<1024, 256, 0, stream>>>(Wo, Wt + (size_t)3072 * 1024);
  k_qkv<<<dim3(24, 64), 256, 0, stream>>>(xn, Wt, bq, bk, bv, Qb, Kb, Vtb);
  k_stats<<<dim3(16, 64), 256, 0, stream>>>(Qb, Kb, cGp);
  k_attn<<<dim3(16, 64), 256, 0, stream>>>(Qb, Kb, Vtb, cGp, XhB);
  k_out<<<dim3(8, 64), 256, 0, stream>>>(XhB, Wt + (size_t)3072 * 1024, bo, x, out);
}

// Round 9
// 511.137 us; speedup vs baseline: 1.2498x; 1.2498x over previous
//
#include <hip/hip_runtime.h>

#define DEV __device__ __forceinline__

// ---------- vector types ----------
typedef float          f32x4  __attribute__((ext_vector_type(4)));
typedef unsigned int   u32x4  __attribute__((ext_vector_type(4)));
typedef unsigned short u16x4  __attribute__((ext_vector_type(4)));
typedef __bf16         vbf8   __attribute__((ext_vector_type(8)));
typedef short          vs8    __attribute__((ext_vector_type(8)));

typedef f32x4 f32x4_a __attribute__((may_alias));
typedef u32x4 u32x4_a __attribute__((may_alias));
typedef u16x4 u16x4_a __attribute__((may_alias));

// ---------- bf16 helpers (RNE) ----------
DEV unsigned short f2bf(float f) {
  unsigned int u = __float_as_uint(f);
  u += 0x7fffu + ((u >> 16) & 1u);
  return (unsigned short)(u >> 16);
}

// ---------- MFMA shim (v8 bf16 vs v8 i16 builtin prototypes) ----------
struct MfmaNope {};
template <class T, class U> struct SameT { static constexpr bool value = false; };
template <class T> struct SameT<T, T> { static constexpr bool value = true; };

template <typename A>
DEV auto mfma_try(A a, A b, f32x4 c, int)
    -> decltype(__builtin_amdgcn_mfma_f32_16x16x32_bf16(a, b, c, 0, 0, 0)) {
  return __builtin_amdgcn_mfma_f32_16x16x32_bf16(a, b, c, 0, 0, 0);
}
template <typename A>
DEV MfmaNope mfma_try(A, A, f32x4, long) { return MfmaNope{}; }

template <typename I4 = u32x4>
DEV f32x4 mfma_bf16(I4 a, I4 b, f32x4 c) {
  auto r = mfma_try(__builtin_bit_cast(vbf8, a), __builtin_bit_cast(vbf8, b), c, 0);
  if constexpr (SameT<decltype(r), MfmaNope>::value) {
    return mfma_try(__builtin_bit_cast(vs8, a), __builtin_bit_cast(vs8, b), c, 0);
  } else {
    return r;
  }
}

// Fragment layout (16x16x32 bf16):
//   A[m][k]: m=lane&15, k=(lane>>4)*8+j ; B[k][n]: n=lane&15, k=(lane>>4)*8+j
//   C[m][n]: n=lane&15, m=(lane>>4)*4+reg
// Softmax in exp2-domain: Q pre-scaled by 0.125*log2(e) in k_qkv,
// k_stats emits c[s] = max_q(S') + log2(sum_q 2^(S'-max)), k_attn: P=2^(S'-c).
// r7 post-mortem: direct-global V gather caused 457MB HBM fetch (4x wave
// duplication + cross-XCD spread). Fix: V back in LDS (shared per block),
// s-tile 64 so Ks+Vts+Ps = 28KB -> 4 blocks/CU, and bh-major grid so all
// blocks sharing a (K,V,Q) panel sit on one XCD's L2 (id%8 = bh%8).
#define QSCL 0.18033688011112042f  // 0.125 * log2(e)

// =====================================================================
// Kernel 1: LayerNorm fp32 -> bf16   (8192 rows of 1024)
// =====================================================================
__global__ __launch_bounds__(256) void k_ln(const float* __restrict__ x,
                                            unsigned short* __restrict__ xn) {
  const int row = blockIdx.x;
  const int t = threadIdx.x;
  f32x4 v = *reinterpret_cast<const f32x4_a*>(x + (size_t)row * 1024 + t * 4);
  float s = v[0] + v[1] + v[2] + v[3];
  float q = v[0]*v[0] + v[1]*v[1] + v[2]*v[2] + v[3]*v[3];
#pragma unroll
  for (int o = 32; o > 0; o >>= 1) { s += __shfl_xor(s, o); q += __shfl_xor(q, o); }
  __shared__ float rs_[4], rq_[4];
  const int w = t >> 6;
  if ((t & 63) == 0) { rs_[w] = s; rq_[w] = q; }
  __syncthreads();
  s = rs_[0] + rs_[1] + rs_[2] + rs_[3];
  q = rq_[0] + rq_[1] + rq_[2] + rq_[3];
  const float mu = s * (1.0f / 1024.0f);
  const float rstd = rsqrtf(q * (1.0f / 1024.0f) - mu * mu + 1e-5f);
  u16x4 o;
#pragma unroll
  for (int i = 0; i < 4; ++i) o[i] = f2bf((v[i] - mu) * rstd);
  *reinterpret_cast<u16x4_a*>(xn + (size_t)row * 1024 + t * 4) = o;
}

// =====================================================================
// Kernel 2a: repack Wq/Wk/Wv [16][1024][64] fp32 -> Wt rows [3072][1024] bf16
// =====================================================================
__global__ __launch_bounds__(256) void k_repw(const float* __restrict__ Wq,
                                              const float* __restrict__ Wk,
                                              const float* __restrict__ Wv,
                                              unsigned short* __restrict__ Wt) {
  __shared__ float ld[64][65];
  const int d0 = blockIdx.x * 64;
  const int sh = blockIdx.y;
  const int sel = sh >> 4, h = sh & 15;
  const float* W = (sel == 0) ? Wq : (sel == 1) ? Wk : Wv;
  const float* src = W + (size_t)h * 1024 * 64;
  const int t = threadIdx.x;
#pragma unroll
  for (int r = 0; r < 16; ++r) {
    const int e = t + 256 * r;
    const int dl = e >> 6, k = e & 63;
    ld[dl][k] = src[(size_t)(d0 + dl) * 64 + k];
  }
  __syncthreads();
#pragma unroll
  for (int r = 0; r < 16; ++r) {
    const int e = t + 256 * r;
    const int k = e >> 6, dl = e & 63;
    Wt[(size_t)(sel * 1024 + h * 64 + k) * 1024 + d0 + dl] = f2bf(ld[dl][k]);
  }
}

// Kernel 2b: cast Wo fp32 -> bf16
__global__ __launch_bounds__(256) void k_repo(const float* __restrict__ Wo,
                                              unsigned short* __restrict__ WoT) {
  const int j = blockIdx.x, t = threadIdx.x;
  f32x4 v = *reinterpret_cast<const f32x4_a*>(Wo + (size_t)j * 1024 + t * 4);
  u16x4 o;
#pragma unroll
  for (int i = 0; i < 4; ++i) o[i] = f2bf(v[i]);
  *reinterpret_cast<u16x4_a*>(WoT + (size_t)j * 1024 + t * 4) = o;
}

// =====================================================================
// Kernel 3: QKV GEMM. Q pre-scaled by QSCL; V written TRANSPOSED
// Vt[bh][64][2048] via u16x4 stores (r-quad = 4 consecutive s). grid (24,64).
// =====================================================================
__global__ __launch_bounds__(256) void k_qkv(const unsigned short* __restrict__ A,
                                             const unsigned short* __restrict__ Bt,
                                             const float* __restrict__ bq,
                                             const float* __restrict__ bk,
                                             const float* __restrict__ bv,
                                             unsigned short* __restrict__ Qo,
                                             unsigned short* __restrict__ Ko,
                                             unsigned short* __restrict__ Vt) {
  __shared__ __align__(16) unsigned short As[128][72];
  __shared__ __align__(16) unsigned short Bs[128][72];
  const int bn = blockIdx.x, bm = blockIdx.y;
  const int t = threadIdx.x;
  const int w = t >> 6, lane = t & 63, l15 = lane & 15, g = lane >> 4;
  const int wm = w & 1, wn = w >> 1;
  f32x4 acc[4][4] = {};
  const int am0 = bm * 128, bn0 = bn * 128;
  for (int kt = 0; kt < 16; ++kt) {
    const int k0 = kt * 64;
    __syncthreads();
#pragma unroll
    for (int r = 0; r < 4; ++r) {
      const int ci = t + 256 * r;
      const int row = ci >> 3, c8 = (ci & 7) * 8;
      *reinterpret_cast<u32x4_a*>(&As[row][c8]) =
          *reinterpret_cast<const u32x4_a*>(A + (size_t)(am0 + row) * 1024 + k0 + c8);
      *reinterpret_cast<u32x4_a*>(&Bs[row][c8]) =
          *reinterpret_cast<const u32x4_a*>(Bt + (size_t)(bn0 + row) * 1024 + k0 + c8);
    }
    __syncthreads();
#pragma unroll
    for (int kf = 0; kf < 2; ++kf) {
      u32x4 af[4], bf[4];
#pragma unroll
      for (int i = 0; i < 4; ++i)
        af[i] = *reinterpret_cast<const u32x4_a*>(&As[wm * 64 + i * 16 + l15][kf * 32 + g * 8]);
#pragma unroll
      for (int j = 0; j < 4; ++j)
        bf[j] = *reinterpret_cast<const u32x4_a*>(&Bs[wn * 64 + j * 16 + l15][kf * 32 + g * 8]);
#pragma unroll
      for (int i = 0; i < 4; ++i)
#pragma unroll
        for (int j = 0; j < 4; ++j)
          acc[i][j] = mfma_bf16(af[i], bf[j], acc[i][j]);
    }
  }
  const int sel = bn0 >> 10;
  if (sel == 2) {
    // V^T epilogue: Vt[(b*16+h)*64 + v][s], r-quad = 4 consecutive s
#pragma unroll
    for (int j = 0; j < 4; ++j) {
      const int n10 = (bn0 + wn * 64 + j * 16 + l15) & 1023;
      const float bval = bv[n10];
      const int h = n10 >> 6, vv = n10 & 63;
#pragma unroll
      for (int i = 0; i < 4; ++i) {
        const int m0 = am0 + wm * 64 + i * 16 + g * 4;
        const int bidx = m0 >> 11, s = m0 & 2047;
        u16x4 ov;
#pragma unroll
        for (int r = 0; r < 4; ++r) ov[r] = f2bf(acc[i][j][r] + bval);
        *reinterpret_cast<u16x4_a*>(
            &Vt[((size_t)(bidx * 16 + h) * 64 + vv) * 2048 + s]) = ov;
      }
    }
  } else {
    const float* bias = (sel == 0) ? bq : bk;
    unsigned short* Out = (sel == 0) ? Qo : Ko;
    const float oscl = (sel == 0) ? QSCL : 1.0f;  // fold 1/8*log2e into Q
#pragma unroll
    for (int j = 0; j < 4; ++j) {
      const int n10 = (bn0 + wn * 64 + j * 16 + l15) & 1023;
      const float bval = bias[n10];
      const int h = n10 >> 6, kk = n10 & 63;
#pragma unroll
      for (int i = 0; i < 4; ++i) {
#pragma unroll
        for (int r = 0; r < 4; ++r) {
          const int m = am0 + wm * 64 + i * 16 + g * 4 + r;
          const int bidx = m >> 11, s = m & 2047;
          Out[((size_t)(bidx * 16 + h) * 2048 + s) * 64 + kk] =
              f2bf((acc[i][j][r] + bval) * oscl);
        }
      }
    }
  }
}

// =====================================================================
// Kernel 4: column softmax stats (exp2 domain).  grid (64, 16) bh-major:
//   x=bh, y=sblk -> all 16 sblk blocks of one bh on one XCD (Q panel L2-hot).
//   c[s] = max_q(S') + log2(sum_q 2^(S'-max)).
// =====================================================================
__global__ __launch_bounds__(256, 4) void k_stats(const unsigned short* __restrict__ Q,
                                                  const unsigned short* __restrict__ K,
                                                  float* __restrict__ cG) {
  __shared__ __align__(16) unsigned short Ks[128][72];
  __shared__ float redM[4][128], redL[4][128];
  const int bh = blockIdx.x, sblk = blockIdx.y;
  const unsigned short* Qh = Q + (size_t)bh * 2048 * 64;
  const unsigned short* Kh = K + (size_t)bh * 2048 * 64;
  const int t = threadIdx.x;
  const int w = t >> 6, lane = t & 63, l15 = lane & 15, g = lane >> 4;

#pragma unroll
  for (int r = 0; r < 4; ++r) {
    const int ci = t + 256 * r;
    const int row = ci >> 3, c8 = (ci & 7) * 8;
    *reinterpret_cast<u32x4_a*>(&Ks[row][c8]) =
        *reinterpret_cast<const u32x4_a*>(Kh + ((size_t)sblk * 128 + row) * 64 + c8);
  }
  __syncthreads();

  // hoist K B-frags once (read-only for whole kernel)
  u32x4 bf[2][8];
#pragma unroll
  for (int kf = 0; kf < 2; ++kf)
#pragma unroll
    for (int n = 0; n < 8; ++n)
      bf[kf][n] = *reinterpret_cast<const u32x4_a*>(&Ks[n * 16 + l15][kf * 32 + g * 8]);

  float m_run[8], l_run[8];
#pragma unroll
  for (int n = 0; n < 8; ++n) { m_run[n] = -1e30f; l_run[n] = 0.0f; }

  for (int qt = 0; qt < 16; ++qt) {
    f32x4 acc[2][8] = {};
#pragma unroll
    for (int kf = 0; kf < 2; ++kf) {
      u32x4 af[2];
#pragma unroll
      for (int i = 0; i < 2; ++i)
        af[i] = *reinterpret_cast<const u32x4_a*>(
            Qh + ((size_t)qt * 128 + w * 32 + i * 16 + l15) * 64 + kf * 32 + g * 8);
#pragma unroll
      for (int i = 0; i < 2; ++i)
#pragma unroll
        for (int n = 0; n < 8; ++n)
          acc[i][n] = mfma_bf16(af[i], bf[kf][n], acc[i][n]);
    }
#pragma unroll
    for (int n = 0; n < 8; ++n) {
      float mt = -1e30f;
#pragma unroll
      for (int i = 0; i < 2; ++i)
#pragma unroll
        for (int r = 0; r < 4; ++r) mt = fmaxf(mt, acc[i][n][r]);
      mt = fmaxf(mt, __shfl_xor(mt, 16));
      mt = fmaxf(mt, __shfl_xor(mt, 32));
      const float mn = fmaxf(m_run[n], mt);
      float st = 0.0f;
#pragma unroll
      for (int i = 0; i < 2; ++i)
#pragma unroll
        for (int r = 0; r < 4; ++r) st += exp2f(acc[i][n][r] - mn);
      st += __shfl_xor(st, 16);
      st += __shfl_xor(st, 32);
      l_run[n] = l_run[n] * exp2f(m_run[n] - mn) + st;
      m_run[n] = mn;
    }
  }
  if (lane < 16) {
#pragma unroll
    for (int n = 0; n < 8; ++n) {
      redM[w][n * 16 + l15] = m_run[n];
      redL[w][n * 16 + l15] = l_run[n];
    }
  }
  __syncthreads();
  if (t < 128) {
    float m = fmaxf(fmaxf(redM[0][t], redM[1][t]), fmaxf(redM[2][t], redM[3][t]));
    float l = 0.0f;
#pragma unroll
    for (int ww = 0; ww < 4; ++ww) l += redL[ww][t] * exp2f(redM[ww][t] - m);
    cG[(size_t)bh * 2048 + sblk * 128 + t] = m + log2f(l);
  }
}

// =====================================================================
// Kernel 5: PV pass.  O[q,v] = sum_s 2^(S'[q,s]-c[s]) * V[s,v].
// s-tile = 64.  LDS: Ks[64][72] + Vts[64][72] + Ps[128][40] = 28KB
// -> 4 blocks/CU.  V^T staged by straight b128 copies (shared by 4 waves).
// PV per 32-s quarter: P->Ps (wave-private rows, same-wave DS order, no
// barrier) then 8 MFMA.  grid (64, 16) bh-major: x=bh, y=qb.
// =====================================================================
__global__ __launch_bounds__(256, 4) void k_attn(const unsigned short* __restrict__ Q,
                                                 const unsigned short* __restrict__ K,
                                                 const unsigned short* __restrict__ Vt,
                                                 const float* __restrict__ cG,
                                                 unsigned short* __restrict__ Xh) {
  __shared__ __align__(16) unsigned short Ks[64][72];
  __shared__ __align__(16) unsigned short Vts[64][72];
  __shared__ __align__(16) unsigned short Ps[128][40];
  const int bh = blockIdx.x, qb = blockIdx.y;
  const int b = bh >> 4, h = bh & 15;
  const unsigned short* Qh  = Q  + (size_t)bh * 2048 * 64;
  const unsigned short* Kh  = K  + (size_t)bh * 2048 * 64;
  const unsigned short* Vth = Vt + (size_t)bh * 64 * 2048;
  const float* cH = cG + (size_t)bh * 2048;
  const int t = threadIdx.x;
  const int w = t >> 6, lane = t & 63, l15 = lane & 15, g = lane >> 4;

  // hoist Q fragments (wave-private rows)
  u32x4 aq[2][2];
#pragma unroll
  for (int i = 0; i < 2; ++i)
#pragma unroll
    for (int kf = 0; kf < 2; ++kf)
      aq[i][kf] = *reinterpret_cast<const u32x4_a*>(
          Qh + ((size_t)qb * 128 + w * 32 + i * 16 + l15) * 64 + kf * 32 + g * 8);

  f32x4 oacc[2][4] = {};

  for (int st = 0; st < 32; ++st) {
    const int s0 = st * 64;
    __syncthreads();
#pragma unroll
    for (int r = 0; r < 2; ++r) {
      const int e = t + 256 * r;
      const int row = e >> 3, c8 = (e & 7) * 8;
      *reinterpret_cast<u32x4_a*>(&Ks[row][c8]) =
          *reinterpret_cast<const u32x4_a*>(Kh + ((size_t)s0 + row) * 64 + c8);
      *reinterpret_cast<u32x4_a*>(&Vts[row][c8]) =
          *reinterpret_cast<const u32x4_a*>(Vth + (size_t)row * 2048 + s0 + c8);
    }
    __syncthreads();

    // S' = Q'K^T  (rows: this wave's 32 q; cols: 64 s), exp2 domain
    f32x4 sacc[2][4] = {};
#pragma unroll
    for (int kf = 0; kf < 2; ++kf) {
      u32x4 bfr[4];
#pragma unroll
      for (int n = 0; n < 4; ++n)
        bfr[n] = *reinterpret_cast<const u32x4_a*>(&Ks[n * 16 + l15][kf * 32 + g * 8]);
#pragma unroll
      for (int i = 0; i < 2; ++i)
#pragma unroll
        for (int n = 0; n < 4; ++n)
          sacc[i][n] = mfma_bf16(aq[i][kf], bfr[n], sacc[i][n]);
    }

    // two quarters of 32 s-columns each: P -> Ps (wave-private) -> 8 MFMA
#pragma unroll
    for (int qtr = 0; qtr < 2; ++qtr) {
#pragma unroll
      for (int n2 = 0; n2 < 2; ++n2) {
        const int n = qtr * 2 + n2;
        const float cv = cH[s0 + n * 16 + l15];
#pragma unroll
        for (int i = 0; i < 2; ++i)
#pragma unroll
          for (int r = 0; r < 4; ++r)
            Ps[w * 32 + i * 16 + g * 4 + r][n2 * 16 + l15] =
                f2bf(exp2f(sacc[i][n][r] - cv));
      }
      u32x4 pa[2], bvv[4];
#pragma unroll
      for (int i = 0; i < 2; ++i)
        pa[i] = *reinterpret_cast<const u32x4_a*>(&Ps[w * 32 + i * 16 + l15][g * 8]);
#pragma unroll
      for (int nv = 0; nv < 4; ++nv)
        bvv[nv] = *reinterpret_cast<const u32x4_a*>(
            &Vts[nv * 16 + l15][qtr * 32 + g * 8]);
#pragma unroll
      for (int i = 0; i < 2; ++i)
#pragma unroll
        for (int nv = 0; nv < 4; ++nv)
          oacc[i][nv] = mfma_bf16(pa[i], bvv[nv], oacc[i][nv]);
    }
  }

  // write O to Xh[b*2048+q][h*64+v]
#pragma unroll
  for (int i = 0; i < 2; ++i)
#pragma unroll
    for (int n = 0; n < 4; ++n)
#pragma unroll
      for (int r = 0; r < 4; ++r) {
        const int qrow = qb * 128 + w * 32 + i * 16 + g * 4 + r;
        const int vcol = n * 16 + l15;
        Xh[((size_t)b * 2048 + qrow) * 1024 + h * 64 + vcol] = f2bf(oacc[i][n][r]);
      }
}

// =====================================================================
// Kernel 6: output projection + bias + residual -> d_out fp32. grid (8,64).
// =====================================================================
__global__ __launch_bounds__(256) void k_out(const unsigned short* __restrict__ A,
                                             const unsigned short* __restrict__ Bt,
                                             const float* __restrict__ bo,
                                             const float* __restrict__ xres,
                                             float* __restrict__ out) {
  __shared__ __align__(16) unsigned short As[128][72];
  __shared__ __align__(16) unsigned short Bs[128][72];
  const int bn = blockIdx.x, bm = blockIdx.y;
  const int t = threadIdx.x;
  const int w = t >> 6, lane = t & 63, l15 = lane & 15, g = lane >> 4;
  const int wm = w & 1, wn = w >> 1;
  f32x4 acc[4][4] = {};
  const int am0 = bm * 128, bn0 = bn * 128;
  for (int kt = 0; kt < 16; ++kt) {
    const int k0 = kt * 64;
    __syncthreads();
#pragma unroll
    for (int r = 0; r < 4; ++r) {
      const int ci = t + 256 * r;
      const int row = ci >> 3, c8 = (ci & 7) * 8;
      *reinterpret_cast<u32x4_a*>(&As[row][c8]) =
          *reinterpret_cast<const u32x4_a*>(A + (size_t)(am0 + row) * 1024 + k0 + c8);
      *reinterpret_cast<u32x4_a*>(&Bs[row][c8]) =
          *reinterpret_cast<const u32x4_a*>(Bt + (size_t)(bn0 + row) * 1024 + k0 + c8);
    }
    __syncthreads();
#pragma unroll
    for (int kf = 0; kf < 2; ++kf) {
      u32x4 af[4], bf[4];
#pragma unroll
      for (int i = 0; i < 4; ++i)
        af[i] = *reinterpret_cast<const u32x4_a*>(&As[wm * 64 + i * 16 + l15][kf * 32 + g * 8]);
#pragma unroll
      for (int j = 0; j < 4; ++j)
        bf[j] = *reinterpret_cast<const u32x4_a*>(&Bs[wn * 64 + j * 16 + l15][kf * 32 + g * 8]);
#pragma unroll
      for (int i = 0; i < 4; ++i)
#pragma unroll
        for (int j = 0; j < 4; ++j)
          acc[i][j] = mfma_bf16(af[i], bf[j], acc[i][j]);
    }
  }
#pragma unroll
  for (int j = 0; j < 4; ++j) {
    const int col = bn0 + wn * 64 + j * 16 + l15;
    const float bov = bo[col];
#pragma unroll
    for (int i = 0; i < 4; ++i) {
#pragma unroll
      for (int r = 0; r < 4; ++r) {
        const int row = am0 + wm * 64 + i * 16 + g * 4 + r;
        out[(size_t)row * 1024 + col] =
            acc[i][j][r] + bov + xres[(size_t)row * 1024 + col];
      }
    }
  }
}

// =====================================================================
// Launch
// =====================================================================
extern "C" void kernel_launch(void* const* d_in, const int* in_sizes, int n_in,
                              void* d_out, int out_size, void* d_ws, size_t ws_size,
                              hipStream_t stream) {
  const float* x  = (const float*)d_in[0];
  const float* Wq = (const float*)d_in[1];
  const float* bq = (const float*)d_in[2];
  const float* Wk = (const float*)d_in[3];
  const float* bk = (const float*)d_in[4];
  const float* Wv = (const float*)d_in[5];
  const float* bv = (const float*)d_in[6];
  const float* Wo = (const float*)d_in[7];
  const float* bo = (const float*)d_in[8];
  float* out = (float*)d_out;

  unsigned short* xn  = (unsigned short*)d_ws;          // 8192*1024 bf16
  unsigned short* Wt  = xn + (size_t)8192 * 1024;       // 4096*1024 bf16
  unsigned short* Qb  = Wt + (size_t)4096 * 1024;       // [bh][2048][64] (pre-scaled)
  unsigned short* Kb  = Qb + (size_t)8192 * 1024;       // [bh][2048][64]
  unsigned short* Vtb = Kb + (size_t)8192 * 1024;       // [bh][64][2048]  (V^T)
  float* cGp  = (float*)(Vtb + (size_t)8192 * 1024);    // [bh][2048] fused stats
  unsigned short* XhB = (unsigned short*)(cGp + 2 * 131072);

  k_ln<<<8192, 256, 0, stream>>>(x, xn);
  k_repw<<<dim3(16, 48), 256, 0, stream>>>(Wq, Wk, Wv, Wt);
  k_repo<<<1024, 256, 0, stream>>>(Wo, Wt + (size_t)3072 * 1024);
  k_qkv<<<dim3(24, 64), 256, 0, stream>>>(xn, Wt, bq, bk, bv, Qb, Kb, Vtb);
  k_stats<<<dim3(64, 16), 256, 0, stream>>>(Qb, Kb, cGp);
  k_attn<<<dim3(64, 16), 256, 0, stream>>>(Qb, Kb, Vtb, cGp, XhB);
  k_out<<<dim3(8, 64), 256, 0, stream>>>(XhB, Wt + (size_t)3072 * 1024, bo, x, out);
}

// Round 10
// 415.549 us; speedup vs baseline: 1.5373x; 1.2300x over previous
//
#include <hip/hip_runtime.h>

#define DEV __device__ __forceinline__

// ---------- vector types ----------
typedef float          f32x4  __attribute__((ext_vector_type(4)));
typedef unsigned int   u32x4  __attribute__((ext_vector_type(4)));
typedef unsigned short u16x4  __attribute__((ext_vector_type(4)));
typedef __bf16         vbf8   __attribute__((ext_vector_type(8)));
typedef short          vs8    __attribute__((ext_vector_type(8)));

typedef f32x4 f32x4_a __attribute__((may_alias));
typedef u32x4 u32x4_a __attribute__((may_alias));
typedef u16x4 u16x4_a __attribute__((may_alias));

// ---------- bf16 helpers (RNE) ----------
DEV unsigned short f2bf(float f) {
  unsigned int u = __float_as_uint(f);
  u += 0x7fffu + ((u >> 16) & 1u);
  return (unsigned short)(u >> 16);
}

// ---------- MFMA shim (v8 bf16 vs v8 i16 builtin prototypes) ----------
struct MfmaNope {};
template <class T, class U> struct SameT { static constexpr bool value = false; };
template <class T> struct SameT<T, T> { static constexpr bool value = true; };

template <typename A>
DEV auto mfma_try(A a, A b, f32x4 c, int)
    -> decltype(__builtin_amdgcn_mfma_f32_16x16x32_bf16(a, b, c, 0, 0, 0)) {
  return __builtin_amdgcn_mfma_f32_16x16x32_bf16(a, b, c, 0, 0, 0);
}
template <typename A>
DEV MfmaNope mfma_try(A, A, f32x4, long) { return MfmaNope{}; }

template <typename I4 = u32x4>
DEV f32x4 mfma_bf16(I4 a, I4 b, f32x4 c) {
  auto r = mfma_try(__builtin_bit_cast(vbf8, a), __builtin_bit_cast(vbf8, b), c, 0);
  if constexpr (SameT<decltype(r), MfmaNope>::value) {
    return mfma_try(__builtin_bit_cast(vs8, a), __builtin_bit_cast(vs8, b), c, 0);
  } else {
    return r;
  }
}

// Fragment layout (16x16x32 bf16):
//   A[m][k]: m=lane&15, k=(lane>>4)*8+j ; B[k][n]: n=lane&15, k=(lane>>4)*8+j
//   C[m][n]: n=lane&15, m=(lane>>4)*4+reg
// Softmax in exp2-domain: Q pre-scaled by 0.125*log2(e) in k_qkv.
// r9: k_stats uses FIXED shift (no online max): c[s] = 16 + log2(sum_q
// 2^(S'-16)).  Safe: S'~N(0,1.44), max ~9 over 2.7e8 samples; sum<=16.
// k_attn: P = 2^(S'-c).
#define QSCL 0.18033688011112042f  // 0.125 * log2(e)
#define SSHIFT 16.0f

// =====================================================================
// Kernel 1: LayerNorm fp32 -> bf16   (8192 rows of 1024)
// =====================================================================
__global__ __launch_bounds__(256) void k_ln(const float* __restrict__ x,
                                            unsigned short* __restrict__ xn) {
  const int row = blockIdx.x;
  const int t = threadIdx.x;
  f32x4 v = *reinterpret_cast<const f32x4_a*>(x + (size_t)row * 1024 + t * 4);
  float s = v[0] + v[1] + v[2] + v[3];
  float q = v[0]*v[0] + v[1]*v[1] + v[2]*v[2] + v[3]*v[3];
#pragma unroll
  for (int o = 32; o > 0; o >>= 1) { s += __shfl_xor(s, o); q += __shfl_xor(q, o); }
  __shared__ float rs_[4], rq_[4];
  const int w = t >> 6;
  if ((t & 63) == 0) { rs_[w] = s; rq_[w] = q; }
  __syncthreads();
  s = rs_[0] + rs_[1] + rs_[2] + rs_[3];
  q = rq_[0] + rq_[1] + rq_[2] + rq_[3];
  const float mu = s * (1.0f / 1024.0f);
  const float rstd = rsqrtf(q * (1.0f / 1024.0f) - mu * mu + 1e-5f);
  u16x4 o;
#pragma unroll
  for (int i = 0; i < 4; ++i) o[i] = f2bf((v[i] - mu) * rstd);
  *reinterpret_cast<u16x4_a*>(xn + (size_t)row * 1024 + t * 4) = o;
}

// =====================================================================
// Kernel 2a: repack Wq/Wk/Wv [16][1024][64] fp32 -> Wt rows [3072][1024] bf16
// =====================================================================
__global__ __launch_bounds__(256) void k_repw(const float* __restrict__ Wq,
                                              const float* __restrict__ Wk,
                                              const float* __restrict__ Wv,
                                              unsigned short* __restrict__ Wt) {
  __shared__ float ld[64][65];
  const int d0 = blockIdx.x * 64;
  const int sh = blockIdx.y;
  const int sel = sh >> 4, h = sh & 15;
  const float* W = (sel == 0) ? Wq : (sel == 1) ? Wk : Wv;
  const float* src = W + (size_t)h * 1024 * 64;
  const int t = threadIdx.x;
#pragma unroll
  for (int r = 0; r < 16; ++r) {
    const int e = t + 256 * r;
    const int dl = e >> 6, k = e & 63;
    ld[dl][k] = src[(size_t)(d0 + dl) * 64 + k];
  }
  __syncthreads();
#pragma unroll
  for (int r = 0; r < 16; ++r) {
    const int e = t + 256 * r;
    const int k = e >> 6, dl = e & 63;
    Wt[(size_t)(sel * 1024 + h * 64 + k) * 1024 + d0 + dl] = f2bf(ld[dl][k]);
  }
}

// Kernel 2b: cast Wo fp32 -> bf16
__global__ __launch_bounds__(256) void k_repo(const float* __restrict__ Wo,
                                              unsigned short* __restrict__ WoT) {
  const int j = blockIdx.x, t = threadIdx.x;
  f32x4 v = *reinterpret_cast<const f32x4_a*>(Wo + (size_t)j * 1024 + t * 4);
  u16x4 o;
#pragma unroll
  for (int i = 0; i < 4; ++i) o[i] = f2bf(v[i]);
  *reinterpret_cast<u16x4_a*>(WoT + (size_t)j * 1024 + t * 4) = o;
}

// =====================================================================
// Kernel 3: QKV GEMM. Q pre-scaled by QSCL; V written TRANSPOSED
// Vt[bh][64][2048] via u16x4 stores (r-quad = 4 consecutive s). grid (24,64).
// =====================================================================
__global__ __launch_bounds__(256) void k_qkv(const unsigned short* __restrict__ A,
                                             const unsigned short* __restrict__ Bt,
                                             const float* __restrict__ bq,
                                             const float* __restrict__ bk,
                                             const float* __restrict__ bv,
                                             unsigned short* __restrict__ Qo,
                                             unsigned short* __restrict__ Ko,
                                             unsigned short* __restrict__ Vt) {
  __shared__ __align__(16) unsigned short As[128][72];
  __shared__ __align__(16) unsigned short Bs[128][72];
  const int bn = blockIdx.x, bm = blockIdx.y;
  const int t = threadIdx.x;
  const int w = t >> 6, lane = t & 63, l15 = lane & 15, g = lane >> 4;
  const int wm = w & 1, wn = w >> 1;
  f32x4 acc[4][4] = {};
  const int am0 = bm * 128, bn0 = bn * 128;
  for (int kt = 0; kt < 16; ++kt) {
    const int k0 = kt * 64;
    __syncthreads();
#pragma unroll
    for (int r = 0; r < 4; ++r) {
      const int ci = t + 256 * r;
      const int row = ci >> 3, c8 = (ci & 7) * 8;
      *reinterpret_cast<u32x4_a*>(&As[row][c8]) =
          *reinterpret_cast<const u32x4_a*>(A + (size_t)(am0 + row) * 1024 + k0 + c8);
      *reinterpret_cast<u32x4_a*>(&Bs[row][c8]) =
          *reinterpret_cast<const u32x4_a*>(Bt + (size_t)(bn0 + row) * 1024 + k0 + c8);
    }
    __syncthreads();
#pragma unroll
    for (int kf = 0; kf < 2; ++kf) {
      u32x4 af[4], bf[4];
#pragma unroll
      for (int i = 0; i < 4; ++i)
        af[i] = *reinterpret_cast<const u32x4_a*>(&As[wm * 64 + i * 16 + l15][kf * 32 + g * 8]);
#pragma unroll
      for (int j = 0; j < 4; ++j)
        bf[j] = *reinterpret_cast<const u32x4_a*>(&Bs[wn * 64 + j * 16 + l15][kf * 32 + g * 8]);
#pragma unroll
      for (int i = 0; i < 4; ++i)
#pragma unroll
        for (int j = 0; j < 4; ++j)
          acc[i][j] = mfma_bf16(af[i], bf[j], acc[i][j]);
    }
  }
  const int sel = bn0 >> 10;
  if (sel == 2) {
    // V^T epilogue: Vt[(b*16+h)*64 + v][s], r-quad = 4 consecutive s
#pragma unroll
    for (int j = 0; j < 4; ++j) {
      const int n10 = (bn0 + wn * 64 + j * 16 + l15) & 1023;
      const float bval = bv[n10];
      const int h = n10 >> 6, vv = n10 & 63;
#pragma unroll
      for (int i = 0; i < 4; ++i) {
        const int m0 = am0 + wm * 64 + i * 16 + g * 4;
        const int bidx = m0 >> 11, s = m0 & 2047;
        u16x4 ov;
#pragma unroll
        for (int r = 0; r < 4; ++r) ov[r] = f2bf(acc[i][j][r] + bval);
        *reinterpret_cast<u16x4_a*>(
            &Vt[((size_t)(bidx * 16 + h) * 64 + vv) * 2048 + s]) = ov;
      }
    }
  } else {
    const float* bias = (sel == 0) ? bq : bk;
    unsigned short* Out = (sel == 0) ? Qo : Ko;
    const float oscl = (sel == 0) ? QSCL : 1.0f;  // fold 1/8*log2e into Q
#pragma unroll
    for (int j = 0; j < 4; ++j) {
      const int n10 = (bn0 + wn * 64 + j * 16 + l15) & 1023;
      const float bval = bias[n10];
      const int h = n10 >> 6, kk = n10 & 63;
#pragma unroll
      for (int i = 0; i < 4; ++i) {
#pragma unroll
        for (int r = 0; r < 4; ++r) {
          const int m = am0 + wm * 64 + i * 16 + g * 4 + r;
          const int bidx = m >> 11, s = m & 2047;
          Out[((size_t)(bidx * 16 + h) * 2048 + s) * 64 + kk] =
              f2bf((acc[i][j][r] + bval) * oscl);
        }
      }
    }
  }
}

// =====================================================================
// Kernel 4: column softmax stats (exp2 domain, fixed shift).
//   c[s] = SSHIFT + log2(sum_q 2^(S'-SSHIFT))   — no online max.
// 512-thread blocks, two 4-wave groups: group g handles s-half
// sblk*256 + g*128 .. +128.  Both groups read the SAME Q A-frags from
// global (L1/L2 dedup) -> issued Q traffic halves vs 128-s blocks.
// K staged once in Ks[256][72] (36.8KB).  grid (64 bh, 8 sblk) bh-major.
// =====================================================================
__global__ __launch_bounds__(512, 2) void k_stats(const unsigned short* __restrict__ Q,
                                                  const unsigned short* __restrict__ K,
                                                  float* __restrict__ cG) {
  __shared__ __align__(16) unsigned short Ks[256][72];
  __shared__ float redL[8][128];
  const int bh = blockIdx.x, sblk = blockIdx.y;
  const unsigned short* Qh = Q + (size_t)bh * 2048 * 64;
  const unsigned short* Kh = K + (size_t)bh * 2048 * 64;
  const int t = threadIdx.x;
  const int w = t >> 6, lane = t & 63, l15 = lane & 15, g = lane >> 4;
  const int grp = w >> 2, wg = w & 3;

#pragma unroll
  for (int r = 0; r < 4; ++r) {
    const int ci = t + 512 * r;
    const int row = ci >> 3, c8 = (ci & 7) * 8;
    *reinterpret_cast<u32x4_a*>(&Ks[row][c8]) =
        *reinterpret_cast<const u32x4_a*>(Kh + ((size_t)sblk * 256 + row) * 64 + c8);
  }
  __syncthreads();

  // hoist this group's K B-frags (read-only for whole kernel)
  u32x4 bf[2][8];
#pragma unroll
  for (int kf = 0; kf < 2; ++kf)
#pragma unroll
    for (int n = 0; n < 8; ++n)
      bf[kf][n] = *reinterpret_cast<const u32x4_a*>(
          &Ks[grp * 128 + n * 16 + l15][kf * 32 + g * 8]);

  float l_run[8];
#pragma unroll
  for (int n = 0; n < 8; ++n) l_run[n] = 0.0f;

  for (int qt = 0; qt < 16; ++qt) {
    f32x4 acc[2][8] = {};
#pragma unroll
    for (int kf = 0; kf < 2; ++kf) {
      u32x4 af[2];
#pragma unroll
      for (int i = 0; i < 2; ++i)
        af[i] = *reinterpret_cast<const u32x4_a*>(
            Qh + ((size_t)qt * 128 + wg * 32 + i * 16 + l15) * 64 + kf * 32 + g * 8);
#pragma unroll
      for (int i = 0; i < 2; ++i)
#pragma unroll
        for (int n = 0; n < 8; ++n)
          acc[i][n] = mfma_bf16(af[i], bf[kf][n], acc[i][n]);
    }
#pragma unroll
    for (int n = 0; n < 8; ++n) {
      float st = 0.0f;
#pragma unroll
      for (int i = 0; i < 2; ++i)
#pragma unroll
        for (int r = 0; r < 4; ++r) st += exp2f(acc[i][n][r] - SSHIFT);
      st += __shfl_xor(st, 16);
      st += __shfl_xor(st, 32);
      l_run[n] += st;
    }
  }
  if (lane < 16) {
#pragma unroll
    for (int n = 0; n < 8; ++n) redL[w][n * 16 + l15] = l_run[n];
  }
  __syncthreads();
  if (t < 256) {
    const int gt = t >> 7, col = t & 127;
    float l = redL[gt * 4][col] + redL[gt * 4 + 1][col] +
              redL[gt * 4 + 2][col] + redL[gt * 4 + 3][col];
    cG[(size_t)bh * 2048 + sblk * 256 + t] = SSHIFT + log2f(l);
  }
}

// =====================================================================
// Kernel 5: PV pass.  O[q,v] = sum_s 2^(S'[q,s]-c[s]) * V[s,v].
// s-tile = 64.  LDS: Ks[64][72] + Vts[64][72] + Ps[128][40] = 28KB
// -> 4 blocks/CU.  V^T staged by straight b128 copies (shared by 4 waves).
// PV per 32-s quarter: P->Ps (wave-private rows, same-wave DS order, no
// barrier) then 8 MFMA.  grid (64, 16) bh-major: x=bh, y=qb.
// =====================================================================
__global__ __launch_bounds__(256, 4) void k_attn(const unsigned short* __restrict__ Q,
                                                 const unsigned short* __restrict__ K,
                                                 const unsigned short* __restrict__ Vt,
                                                 const float* __restrict__ cG,
                                                 unsigned short* __restrict__ Xh) {
  __shared__ __align__(16) unsigned short Ks[64][72];
  __shared__ __align__(16) unsigned short Vts[64][72];
  __shared__ __align__(16) unsigned short Ps[128][40];
  const int bh = blockIdx.x, qb = blockIdx.y;
  const int b = bh >> 4, h = bh & 15;
  const unsigned short* Qh  = Q  + (size_t)bh * 2048 * 64;
  const unsigned short* Kh  = K  + (size_t)bh * 2048 * 64;
  const unsigned short* Vth = Vt + (size_t)bh * 64 * 2048;
  const float* cH = cG + (size_t)bh * 2048;
  const int t = threadIdx.x;
  const int w = t >> 6, lane = t & 63, l15 = lane & 15, g = lane >> 4;

  // hoist Q fragments (wave-private rows)
  u32x4 aq[2][2];
#pragma unroll
  for (int i = 0; i < 2; ++i)
#pragma unroll
    for (int kf = 0; kf < 2; ++kf)
      aq[i][kf] = *reinterpret_cast<const u32x4_a*>(
          Qh + ((size_t)qb * 128 + w * 32 + i * 16 + l15) * 64 + kf * 32 + g * 8);

  f32x4 oacc[2][4] = {};

  for (int st = 0; st < 32; ++st) {
    const int s0 = st * 64;
    __syncthreads();
#pragma unroll
    for (int r = 0; r < 2; ++r) {
      const int e = t + 256 * r;
      const int row = e >> 3, c8 = (e & 7) * 8;
      *reinterpret_cast<u32x4_a*>(&Ks[row][c8]) =
          *reinterpret_cast<const u32x4_a*>(Kh + ((size_t)s0 + row) * 64 + c8);
      *reinterpret_cast<u32x4_a*>(&Vts[row][c8]) =
          *reinterpret_cast<const u32x4_a*>(Vth + (size_t)row * 2048 + s0 + c8);
    }
    __syncthreads();

    // S' = Q'K^T  (rows: this wave's 32 q; cols: 64 s), exp2 domain
    f32x4 sacc[2][4] = {};
#pragma unroll
    for (int kf = 0; kf < 2; ++kf) {
      u32x4 bfr[4];
#pragma unroll
      for (int n = 0; n < 4; ++n)
        bfr[n] = *reinterpret_cast<const u32x4_a*>(&Ks[n * 16 + l15][kf * 32 + g * 8]);
#pragma unroll
      for (int i = 0; i < 2; ++i)
#pragma unroll
        for (int n = 0; n < 4; ++n)
          sacc[i][n] = mfma_bf16(aq[i][kf], bfr[n], sacc[i][n]);
    }

    // two quarters of 32 s-columns each: P -> Ps (wave-private) -> 8 MFMA
#pragma unroll
    for (int qtr = 0; qtr < 2; ++qtr) {
#pragma unroll
      for (int n2 = 0; n2 < 2; ++n2) {
        const int n = qtr * 2 + n2;
        const float cv = cH[s0 + n * 16 + l15];
#pragma unroll
        for (int i = 0; i < 2; ++i)
#pragma unroll
          for (int r = 0; r < 4; ++r)
            Ps[w * 32 + i * 16 + g * 4 + r][n2 * 16 + l15] =
                f2bf(exp2f(sacc[i][n][r] - cv));
      }
      u32x4 pa[2], bvv[4];
#pragma unroll
      for (int i = 0; i < 2; ++i)
        pa[i] = *reinterpret_cast<const u32x4_a*>(&Ps[w * 32 + i * 16 + l15][g * 8]);
#pragma unroll
      for (int nv = 0; nv < 4; ++nv)
        bvv[nv] = *reinterpret_cast<const u32x4_a*>(
            &Vts[nv * 16 + l15][qtr * 32 + g * 8]);
#pragma unroll
      for (int i = 0; i < 2; ++i)
#pragma unroll
        for (int nv = 0; nv < 4; ++nv)
          oacc[i][nv] = mfma_bf16(pa[i], bvv[nv], oacc[i][nv]);
    }
  }

  // write O to Xh[b*2048+q][h*64+v]
#pragma unroll
  for (int i = 0; i < 2; ++i)
#pragma unroll
    for (int n = 0; n < 4; ++n)
#pragma unroll
      for (int r = 0; r < 4; ++r) {
        const int qrow = qb * 128 + w * 32 + i * 16 + g * 4 + r;
        const int vcol = n * 16 + l15;
        Xh[((size_t)b * 2048 + qrow) * 1024 + h * 64 + vcol] = f2bf(oacc[i][n][r]);
      }
}

// =====================================================================
// Kernel 6: output projection + bias + residual -> d_out fp32. grid (8,64).
// =====================================================================
__global__ __launch_bounds__(256) void k_out(const unsigned short* __restrict__ A,
                                             const unsigned short* __restrict__ Bt,
                                             const float* __restrict__ bo,
                                             const float* __restrict__ xres,
                                             float* __restrict__ out) {
  __shared__ __align__(16) unsigned short As[128][72];
  __shared__ __align__(16) unsigned short Bs[128][72];
  const int bn = blockIdx.x, bm = blockIdx.y;
  const int t = threadIdx.x;
  const int w = t >> 6, lane = t & 63, l15 = lane & 15, g = lane >> 4;
  const int wm = w & 1, wn = w >> 1;
  f32x4 acc[4][4] = {};
  const int am0 = bm * 128, bn0 = bn * 128;
  for (int kt = 0; kt < 16; ++kt) {
    const int k0 = kt * 64;
    __syncthreads();
#pragma unroll
    for (int r = 0; r < 4; ++r) {
      const int ci = t + 256 * r;
      const int row = ci >> 3, c8 = (ci & 7) * 8;
      *reinterpret_cast<u32x4_a*>(&As[row][c8]) =
          *reinterpret_cast<const u32x4_a*>(A + (size_t)(am0 + row) * 1024 + k0 + c8);
      *reinterpret_cast<u32x4_a*>(&Bs[row][c8]) =
          *reinterpret_cast<const u32x4_a*>(Bt + (size_t)(bn0 + row) * 1024 + k0 + c8);
    }
    __syncthreads();
#pragma unroll
    for (int kf = 0; kf < 2; ++kf) {
      u32x4 af[4], bf[4];
#pragma unroll
      for (int i = 0; i < 4; ++i)
        af[i] = *reinterpret_cast<const u32x4_a*>(&As[wm * 64 + i * 16 + l15][kf * 32 + g * 8]);
#pragma unroll
      for (int j = 0; j < 4; ++j)
        bf[j] = *reinterpret_cast<const u32x4_a*>(&Bs[wn * 64 + j * 16 + l15][kf * 32 + g * 8]);
#pragma unroll
      for (int i = 0; i < 4; ++i)
#pragma unroll
        for (int j = 0; j < 4; ++j)
          acc[i][j] = mfma_bf16(af[i], bf[j], acc[i][j]);
    }
  }
#pragma unroll
  for (int j = 0; j < 4; ++j) {
    const int col = bn0 + wn * 64 + j * 16 + l15;
    const float bov = bo[col];
#pragma unroll
    for (int i = 0; i < 4; ++i) {
#pragma unroll
      for (int r = 0; r < 4; ++r) {
        const int row = am0 + wm * 64 + i * 16 + g * 4 + r;
        out[(size_t)row * 1024 + col] =
            acc[i][j][r] + bov + xres[(size_t)row * 1024 + col];
      }
    }
  }
}

// =====================================================================
// Launch
// =====================================================================
extern "C" void kernel_launch(void* const* d_in, const int* in_sizes, int n_in,
                              void* d_out, int out_size, void* d_ws, size_t ws_size,
                              hipStream_t stream) {
  const float* x  = (const float*)d_in[0];
  const float* Wq = (const float*)d_in[1];
  const float* bq = (const float*)d_in[2];
  const float* Wk = (const float*)d_in[3];
  const float* bk = (const float*)d_in[4];
  const float* Wv = (const float*)d_in[5];
  const float* bv = (const float*)d_in[6];
  const float* Wo = (const float*)d_in[7];
  const float* bo = (const float*)d_in[8];
  float* out = (float*)d_out;

  unsigned short* xn  = (unsigned short*)d_ws;          // 8192*1024 bf16
  unsigned short* Wt  = xn + (size_t)8192 * 1024;       // 4096*1024 bf16
  unsigned short* Qb  = Wt + (size_t)4096 * 1024;       // [bh][2048][64] (pre-scaled)
  unsigned short* Kb  = Qb + (size_t)8192 * 1024;       // [bh][2048][64]
  unsigned short* Vtb = Kb + (size_t)8192 * 1024;       // [bh][64][2048]  (V^T)
  float* cGp  = (float*)(Vtb + (size_t)8192 * 1024);    // [bh][2048] fused stats
  unsigned short* XhB = (unsigned short*)(cGp + 2 * 131072);

  k_ln<<<8192, 256, 0, stream>>>(x, xn);
  k_repw<<<dim3(16, 48), 256, 0, stream>>>(Wq, Wk, Wv, Wt);
  k_repo<<<1024, 256, 0, stream>>>(Wo, Wt + (size_t)3072 * 1024);
  k_qkv<<<dim3(24, 64), 256, 0, stream>>>(xn, Wt, bq, bk, bv, Qb, Kb, Vtb);
  k_stats<<<dim3(64, 8), 512, 0, stream>>>(Qb, Kb, cGp);
  k_attn<<<dim3(64, 16), 256, 0, stream>>>(Qb, Kb, Vtb, cGp, XhB);
  k_out<<<dim3(8, 64), 256, 0, stream>>>(XhB, Wt + (size_t)3072 * 1024, bo, x, out);
}